// Round 1
// baseline (846.085 us; speedup 1.0000x reference)
//
#include <hip/hip_runtime.h>
#include <float.h>

#define IGNORE_INDEX 255

constexpr int N_IMG = 8;
constexpr int C     = 80;     // num_class * cnum
constexpr int HW    = 65536;  // 256*256
constexpr int NC    = 20;     // num_class
constexpr int CNUM  = 4;
constexpr int P     = 8192;   // num parcel segments

// ---- workspace layout (float indices) ----
// [0, 163840)        seg_sum   (P*NC)
// [163840, 172032)   counts    (P)
// [172032, 172672)   chan_off  (N_IMG*C)
// [172672, 172675)   accums: [0]=div_sum [1]=nll_sum [2]=valid_cnt
// byte 690752:       tgtp (P ints, init -1 via 0xFF memset)
constexpr size_t OFF_SEGSUM = 0;
constexpr size_t OFF_COUNTS = 163840;
constexpr size_t OFF_CHOFF  = 172032;
constexpr size_t OFF_ACC    = 172672;
constexpr size_t BYTE_TGT   = 690752;
constexpr size_t BYTE_ZERO  = 690752;          // zero [0, BYTE_TGT)
constexpr size_t BYTE_TGT_N = P * sizeof(int); // 32768

__device__ __forceinline__ float waveMax(float v) {
#pragma unroll
  for (int o = 32; o > 0; o >>= 1) v = fmaxf(v, __shfl_down(v, o, 64));
  return v;
}
__device__ __forceinline__ float waveSum(float v) {
#pragma unroll
  for (int o = 32; o > 0; o >>= 1) v += __shfl_down(v, o, 64);
  return v;
}

// Kernel 1: per-channel softmax stats over the spatial dim.
// grid = N_IMG*C blocks of 256. chan_off[ch] = max + log(sum(exp(x-max)))
__global__ __launch_bounds__(256) void chan_stats_kernel(
    const float* __restrict__ f, float* __restrict__ chan_off) {
  const int ch = blockIdx.x;
  const float4* base = (const float4*)(f + (size_t)ch * HW);
  const int n4 = HW / 4;  // 16384
  float m = -FLT_MAX;
  for (int i = threadIdx.x; i < n4; i += 256) {
    float4 v = base[i];
    m = fmaxf(m, fmaxf(fmaxf(v.x, v.y), fmaxf(v.z, v.w)));
  }
  __shared__ float sred[4];
  __shared__ float bcast;
  const int wid = threadIdx.x >> 6, lid = threadIdx.x & 63;
  float wm = waveMax(m);
  if (lid == 0) sred[wid] = wm;
  __syncthreads();
  if (threadIdx.x == 0)
    bcast = fmaxf(fmaxf(sred[0], sred[1]), fmaxf(sred[2], sred[3]));
  __syncthreads();
  const float M = bcast;
  float s = 0.f;
  for (int i = threadIdx.x; i < n4; i += 256) {
    float4 v = base[i];  // second pass: L2-resident (256KB/channel)
    s += __expf(v.x - M) + __expf(v.y - M) + __expf(v.z - M) + __expf(v.w - M);
  }
  float ws = waveSum(s);
  __syncthreads();
  if (lid == 0) sred[wid] = ws;
  __syncthreads();
  if (threadIdx.x == 0) {
    float S = sred[0] + sred[1] + sred[2] + sred[3];
    chan_off[ch] = M + logf(S);
  }
}

// Kernel 2: per-pixel work. One thread handles 4 consecutive pixels (float4).
// grid = N_IMG*HW/4/256 = 512 blocks of 256.
__global__ __launch_bounds__(256) void pixel_kernel(
    const float* __restrict__ f, const int* __restrict__ target,
    const int* __restrict__ parcel, const float* __restrict__ chan_off,
    float* __restrict__ seg_sum, float* __restrict__ counts,
    int* __restrict__ tgtp, float* __restrict__ div_acc) {
  const int t4  = blockIdx.x * 256 + threadIdx.x;  // 0 .. N*HW/4-1
  const int img = t4 / (HW / 4);                   // blocks never straddle images
  const int p4  = t4 % (HW / 4);
  const int pix0 = p4 * 4;
  const float* fb = f + (size_t)img * C * HW;

  __shared__ float soff[C];
  if (threadIdx.x < C) soff[threadIdx.x] = chan_off[img * C + threadIdx.x];
  __syncthreads();

  const int4 tv = *(const int4*)(target + (size_t)img * HW + pix0);
  const int4 pv = *(const int4*)(parcel + (size_t)img * HW + pix0);
  int  tarr[4] = {tv.x, tv.y, tv.z, tv.w};
  int  parr[4] = {pv.x, pv.y, pv.z, pv.w};
  bool val[4];
#pragma unroll
  for (int i = 0; i < 4; i++) val[i] = (tarr[i] != IGNORE_INDEX);

  float divs = 0.f;
#pragma unroll
  for (int k = 0; k < NC; k++) {
    float4 dmax = make_float4(-FLT_MAX, -FLT_MAX, -FLT_MAX, -FLT_MAX);
    float4 emax = make_float4(-FLT_MAX, -FLT_MAX, -FLT_MAX, -FLT_MAX);
#pragma unroll
    for (int j = 0; j < CNUM; j++) {
      const int ch = k * CNUM + j;
      float4 v = *(const float4*)(fb + (size_t)ch * HW + pix0);
      const float off = soff[ch];
      dmax.x = fmaxf(dmax.x, v.x); dmax.y = fmaxf(dmax.y, v.y);
      dmax.z = fmaxf(dmax.z, v.z); dmax.w = fmaxf(dmax.w, v.w);
      emax.x = fmaxf(emax.x, __expf(v.x - off));
      emax.y = fmaxf(emax.y, __expf(v.y - off));
      emax.z = fmaxf(emax.z, __expf(v.z - off));
      emax.w = fmaxf(emax.w, __expf(v.w - off));
    }
    divs += emax.x + emax.y + emax.z + emax.w;
    float dm[4] = {dmax.x, dmax.y, dmax.z, dmax.w};
#pragma unroll
    for (int i = 0; i < 4; i++)
      if (val[i]) atomicAdd(&seg_sum[parr[i] * NC + k], dm[i]);
  }
#pragma unroll
  for (int i = 0; i < 4; i++) {
    if (val[i]) {
      atomicAdd(&counts[parr[i]], 1.0f);
      atomicMax(&tgtp[parr[i]], tarr[i]);
    }
  }
  // block-reduce the diversity partial, one atomic per block
  __shared__ float sred[4];
  const int wid = threadIdx.x >> 6, lid = threadIdx.x & 63;
  float wsum = waveSum(divs);
  if (lid == 0) sred[wid] = wsum;
  __syncthreads();
  if (threadIdx.x == 0)
    atomicAdd(div_acc, sred[0] + sred[1] + sred[2] + sred[3]);
}

// Kernel 3: per-segment NLL. grid = P/256 = 32 blocks of 256.
__global__ __launch_bounds__(256) void seg_kernel(
    const float* __restrict__ seg_sum, const float* __restrict__ counts,
    const int* __restrict__ tgtp, float* __restrict__ nll_acc,
    float* __restrict__ vcnt_acc) {
  const int s = blockIdx.x * 256 + threadIdx.x;
  const float cnt = counts[s];
  const float valid = (cnt > 0.f) ? 1.f : 0.f;
  const float inv = 1.f / fmaxf(cnt, 1.f);
  float mean[NC];
  float m = -FLT_MAX;
#pragma unroll
  for (int k = 0; k < NC; k++) {
    mean[k] = seg_sum[s * NC + k] * inv;
    m = fmaxf(m, mean[k]);
  }
  float se = 0.f;
#pragma unroll
  for (int k = 0; k < NC; k++) se += __expf(mean[k] - m);
  const float lse = m + logf(se);
  int t = tgtp[s];
  t = min(max(t, 0), NC - 1);
  const float nll = (lse - mean[t]) * valid;

  __shared__ float sn[4], sv[4];
  const int wid = threadIdx.x >> 6, lid = threadIdx.x & 63;
  float wn = waveSum(nll);
  float wv = waveSum(valid);
  if (lid == 0) { sn[wid] = wn; sv[wid] = wv; }
  __syncthreads();
  if (threadIdx.x == 0) {
    atomicAdd(nll_acc, sn[0] + sn[1] + sn[2] + sn[3]);
    atomicAdd(vcnt_acc, sv[0] + sv[1] + sv[2] + sv[3]);
  }
}

// Kernel 4: write the two scalar outputs.
__global__ void finalize_kernel(const float* __restrict__ acc,
                                float* __restrict__ out) {
  // acc: [0]=div_sum [1]=nll_sum [2]=valid_cnt
  out[0] = acc[1] / fmaxf(acc[2], 1.f);
  out[1] = 1.f - acc[0] / (float)(N_IMG * NC * NC);
}

extern "C" void kernel_launch(void* const* d_in, const int* in_sizes, int n_in,
                              void* d_out, int out_size, void* d_ws,
                              size_t ws_size, hipStream_t stream) {
  const float* features = (const float*)d_in[0];
  const int*   target   = (const int*)d_in[1];
  const int*   parcel   = (const int*)d_in[2];
  // d_in[3..5] = num_segments/cnum/num_class scalars — fixed by the problem.

  float* ws       = (float*)d_ws;
  float* seg_sum  = ws + OFF_SEGSUM;
  float* counts   = ws + OFF_COUNTS;
  float* chan_off = ws + OFF_CHOFF;
  float* acc      = ws + OFF_ACC;  // [div, nll, vcnt]
  int*   tgtp     = (int*)((char*)d_ws + BYTE_TGT);
  float* out      = (float*)d_out;

  hipMemsetAsync(d_ws, 0, BYTE_ZERO, stream);
  hipMemsetAsync((char*)d_ws + BYTE_TGT, 0xFF, BYTE_TGT_N, stream);

  chan_stats_kernel<<<N_IMG * C, 256, 0, stream>>>(features, chan_off);
  pixel_kernel<<<N_IMG * HW / 4 / 256, 256, 0, stream>>>(
      features, target, parcel, chan_off, seg_sum, counts, tgtp, acc + 0);
  seg_kernel<<<P / 256, 256, 0, stream>>>(seg_sum, counts, tgtp, acc + 1,
                                          acc + 2);
  finalize_kernel<<<1, 1, 0, stream>>>(acc, out);
}

// Round 2
// 411.405 us; speedup vs baseline: 2.0566x; 2.0566x over previous
//
#include <hip/hip_runtime.h>
#include <float.h>

#define IGNORE_INDEX 255

constexpr int N_IMG = 8;
constexpr int C     = 80;     // num_class * cnum
constexpr int HW    = 65536;  // 256*256
constexpr int NC    = 20;     // num_class
constexpr int CNUM  = 4;
constexpr int P     = 8192;   // parcel segments
constexpr int NPIX  = N_IMG * HW;  // 524288
constexpr int STRIPES = 4;
constexpr int NCH   = N_IMG * C;   // 640

// ---- sort-path workspace layout (bytes) ----
constexpr size_t B_BD    = 0;                                // NPIX*20 floats
constexpr size_t B_SORT  = (size_t)NPIX * 20 * 4;            // 41943040
constexpr size_t B_CNT   = B_SORT + (size_t)NPIX * 4;        // 44040192
constexpr size_t B_ACC   = B_CNT + (size_t)P * 4;            // 44072960
constexpr size_t B_OFF   = B_ACC + 64;
constexpr size_t B_WOFF  = B_OFF + (size_t)P * 4;
constexpr size_t B_PM    = B_WOFF + (size_t)P * 4;
constexpr size_t B_PS    = B_PM + (size_t)NCH * STRIPES * 4;
constexpr size_t B_CHOFF = B_PS + (size_t)NCH * STRIPES * 4;
constexpr size_t NEED    = B_CHOFF + (size_t)NCH * 4;        // ~44.2 MB

__device__ __forceinline__ float waveMax(float v) {
#pragma unroll
  for (int o = 32; o > 0; o >>= 1) v = fmaxf(v, __shfl_down(v, o, 64));
  return v;
}
__device__ __forceinline__ float waveSum(float v) {
#pragma unroll
  for (int o = 32; o > 0; o >>= 1) v += __shfl_down(v, o, 64);
  return v;
}

// ================= sort-path kernels =================

// K1: per-(channel, stripe) softmax partial stats. grid = 640*4 blocks.
__global__ __launch_bounds__(256) void stats_kernel(
    const float* __restrict__ f, float* __restrict__ pm, float* __restrict__ ps) {
  const int ch = blockIdx.x >> 2, stripe = blockIdx.x & 3;
  const float4* base =
      (const float4*)(f + (size_t)ch * HW + (size_t)stripe * (HW / STRIPES));
  const int n4 = HW / STRIPES / 4;  // 4096
  float m = -FLT_MAX;
  for (int i = threadIdx.x; i < n4; i += 256) {
    float4 v = base[i];
    m = fmaxf(m, fmaxf(fmaxf(v.x, v.y), fmaxf(v.z, v.w)));
  }
  __shared__ float sred[4];
  __shared__ float bcast;
  const int wid = threadIdx.x >> 6, lid = threadIdx.x & 63;
  float wm = waveMax(m);
  if (lid == 0) sred[wid] = wm;
  __syncthreads();
  if (threadIdx.x == 0)
    bcast = fmaxf(fmaxf(sred[0], sred[1]), fmaxf(sred[2], sred[3]));
  __syncthreads();
  const float M = bcast;
  float s = 0.f;
  for (int i = threadIdx.x; i < n4; i += 256) {
    float4 v = base[i];  // L2-hit re-read (64KB chunk)
    s += __expf(v.x - M) + __expf(v.y - M) + __expf(v.z - M) + __expf(v.w - M);
  }
  float wsv = waveSum(s);
  __syncthreads();
  if (lid == 0) sred[wid] = wsv;
  __syncthreads();
  if (threadIdx.x == 0) {
    pm[blockIdx.x] = M;
    ps[blockIdx.x] = sred[0] + sred[1] + sred[2] + sred[3];
  }
}

// K1b: combine 4 stripe partials per channel. <<<1, 640>>>
__global__ void combine_kernel(const float* __restrict__ pm,
                               const float* __restrict__ ps,
                               float* __restrict__ choff) {
  const int ch = threadIdx.x;
  if (ch >= NCH) return;
  float m = -FLT_MAX;
#pragma unroll
  for (int i = 0; i < STRIPES; i++) m = fmaxf(m, pm[ch * STRIPES + i]);
  float s = 0.f;
#pragma unroll
  for (int i = 0; i < STRIPES; i++)
    s += ps[ch * STRIPES + i] * __expf(pm[ch * STRIPES + i] - m);
  choff[ch] = m + logf(s);
}

// K3: histogram of valid pixels per parcel. grid = NPIX/4/256 = 512.
__global__ __launch_bounds__(256) void hist_kernel(
    const int* __restrict__ target, const int* __restrict__ parcel,
    int* __restrict__ cnt) {
  const int t4 = blockIdx.x * 256 + threadIdx.x;
  const int4 tv = ((const int4*)target)[t4];
  const int4 pv = ((const int4*)parcel)[t4];
  if (tv.x != IGNORE_INDEX) atomicAdd(&cnt[pv.x], 1);
  if (tv.y != IGNORE_INDEX) atomicAdd(&cnt[pv.y], 1);
  if (tv.z != IGNORE_INDEX) atomicAdd(&cnt[pv.z], 1);
  if (tv.w != IGNORE_INDEX) atomicAdd(&cnt[pv.w], 1);
}

// K4: exclusive scan of cnt[P] -> offs, woff. <<<1, 1024>>>
__global__ __launch_bounds__(1024) void scan_kernel(
    const int* __restrict__ cnt, int* __restrict__ offs, int* __restrict__ woff) {
  __shared__ int sh[1024];
  const int t = threadIdx.x;
  const int4* c4 = (const int4*)(cnt + t * 8);
  int4 a = c4[0], b = c4[1];
  int c[8] = {a.x, a.y, a.z, a.w, b.x, b.y, b.z, b.w};
  int tot = 0;
#pragma unroll
  for (int j = 0; j < 8; j++) tot += c[j];
  sh[t] = tot;
  __syncthreads();
  for (int d = 1; d < 1024; d <<= 1) {
    int v = (t >= d) ? sh[t - d] : 0;
    __syncthreads();
    sh[t] += v;
    __syncthreads();
  }
  int e = sh[t] - tot;  // exclusive prefix for this thread's 8
#pragma unroll
  for (int j = 0; j < 8; j++) {
    offs[t * 8 + j] = e;
    woff[t * 8 + j] = e;
    e += c[j];
  }
}

// K5: scatter valid pixel ids (packed with target) sorted by parcel.
__global__ __launch_bounds__(256) void scatter_kernel(
    const int* __restrict__ target, const int* __restrict__ parcel,
    int* __restrict__ woff, unsigned* __restrict__ sorted) {
  const int t4 = blockIdx.x * 256 + threadIdx.x;
  const int4 tv = ((const int4*)target)[t4];
  const int4 pv = ((const int4*)parcel)[t4];
  const int pix0 = t4 * 4;
  int tarr[4] = {tv.x, tv.y, tv.z, tv.w};
  int parr[4] = {pv.x, pv.y, pv.z, pv.w};
#pragma unroll
  for (int i = 0; i < 4; i++) {
    if (tarr[i] != IGNORE_INDEX) {
      int pos = atomicAdd(&woff[parr[i]], 1);
      sorted[pos] = ((unsigned)tarr[i] << 19) | (unsigned)(pix0 + i);
    }
  }
}

// K2: per-pixel group-max write (bd) + diversity softmax sum. grid = 2048.
__global__ __launch_bounds__(256) void divbd_kernel(
    const float* __restrict__ f, const float* __restrict__ choff,
    float* __restrict__ bd, float* __restrict__ div_acc) {
  const int pg = blockIdx.x * 256 + threadIdx.x;  // global pixel
  const int img = blockIdx.x >> 8;                // 256 blocks per image
  const int pix = pg & (HW - 1);
  const float* fb = f + (size_t)img * C * HW + pix;
  __shared__ float soff[C];
  if (threadIdx.x < C) soff[threadIdx.x] = choff[img * C + threadIdx.x];
  __syncthreads();
  float dm[NC];
  float divs = 0.f;
#pragma unroll
  for (int k = 0; k < NC; k++) {
    float d = -FLT_MAX, e = -FLT_MAX;
#pragma unroll
    for (int j = 0; j < CNUM; j++) {
      const int ch = k * CNUM + j;
      float v = fb[(size_t)ch * HW];
      d = fmaxf(d, v);
      e = fmaxf(e, v - soff[ch]);  // max(exp(x-off)) == exp(max(x-off))
    }
    dm[k] = d;
    divs += __expf(e);
  }
  float4* o = (float4*)(bd + (size_t)pg * NC);
  o[0] = make_float4(dm[0], dm[1], dm[2], dm[3]);
  o[1] = make_float4(dm[4], dm[5], dm[6], dm[7]);
  o[2] = make_float4(dm[8], dm[9], dm[10], dm[11]);
  o[3] = make_float4(dm[12], dm[13], dm[14], dm[15]);
  o[4] = make_float4(dm[16], dm[17], dm[18], dm[19]);

  __shared__ float sred[4];
  const int wid = threadIdx.x >> 6, lid = threadIdx.x & 63;
  float wsum = waveSum(divs);
  if (lid == 0) sred[wid] = wsum;
  __syncthreads();
  if (threadIdx.x == 0)
    atomicAdd(div_acc, sred[0] + sred[1] + sred[2] + sred[3]);
}

// K6: one wave per parcel: gather bd vectors, mean -> log-softmax -> NLL.
// grid = P/4 = 2048 blocks of 256 (4 waves).
__global__ __launch_bounds__(256) void parcel_kernel(
    const float* __restrict__ bd, const unsigned* __restrict__ sorted,
    const int* __restrict__ cnt, const int* __restrict__ offs,
    float* __restrict__ acc) {
  const int wid = threadIdx.x >> 6, lid = threadIdx.x & 63;
  const int p = blockIdx.x * 4 + wid;
  const int c = cnt[p];
  float sums[NC];
#pragma unroll
  for (int k = 0; k < NC; k++) sums[k] = 0.f;
  int tmax = -1;
  if (c > 0) {
    const int start = offs[p];
    for (int i = lid; i < c; i += 64) {
      const unsigned u = sorted[start + i];
      const int pix = (int)(u & 524287u);
      tmax = max(tmax, (int)(u >> 19));
      const float4* b = (const float4*)(bd + (size_t)pix * NC);
      float4 b0 = b[0], b1 = b[1], b2 = b[2], b3 = b[3], b4 = b[4];
      sums[0] += b0.x;  sums[1] += b0.y;  sums[2] += b0.z;  sums[3] += b0.w;
      sums[4] += b1.x;  sums[5] += b1.y;  sums[6] += b1.z;  sums[7] += b1.w;
      sums[8] += b2.x;  sums[9] += b2.y;  sums[10] += b2.z; sums[11] += b2.w;
      sums[12] += b3.x; sums[13] += b3.y; sums[14] += b3.z; sums[15] += b3.w;
      sums[16] += b4.x; sums[17] += b4.y; sums[18] += b4.z; sums[19] += b4.w;
    }
  }
#pragma unroll
  for (int o = 32; o > 0; o >>= 1) {
#pragma unroll
    for (int k = 0; k < NC; k++) sums[k] += __shfl_xor(sums[k], o, 64);
    tmax = max(tmax, __shfl_xor(tmax, o, 64));
  }
  float nll = 0.f, val = 0.f;
  if (c > 0) {
    const float inv = 1.f / (float)c;
    float mean[NC];
    float m = -FLT_MAX;
#pragma unroll
    for (int k = 0; k < NC; k++) {
      mean[k] = sums[k] * inv;
      m = fmaxf(m, mean[k]);
    }
    float se = 0.f;
#pragma unroll
    for (int k = 0; k < NC; k++) se += __expf(mean[k] - m);
    const float lse = m + logf(se);
    const int t = min(max(tmax, 0), NC - 1);
    nll = lse - mean[t];
    val = 1.f;
  }
  __shared__ float sn[4], sv[4];
  if (lid == 0) { sn[wid] = nll; sv[wid] = val; }
  __syncthreads();
  if (threadIdx.x == 0) {
    atomicAdd(&acc[1], sn[0] + sn[1] + sn[2] + sn[3]);
    atomicAdd(&acc[2], sv[0] + sv[1] + sv[2] + sv[3]);
  }
}

// K7: scalars out. acc: [0]=div_sum [1]=nll_sum [2]=valid_cnt
__global__ void finalize_kernel(const float* __restrict__ acc,
                                float* __restrict__ out) {
  out[0] = acc[1] / fmaxf(acc[2], 1.f);
  out[1] = 1.f - acc[0] / (float)(N_IMG * NC * NC);
}

// ================= fallback path (R1 code, needs ~723KB ws) =================
constexpr size_t OFF_SEGSUM = 0;
constexpr size_t OFF_COUNTS = 163840;
constexpr size_t OFF_CHOFF  = 172032;
constexpr size_t OFF_ACC    = 172672;
constexpr size_t BYTE_TGT   = 690752;
constexpr size_t BYTE_ZERO  = 690752;
constexpr size_t BYTE_TGT_N = P * sizeof(int);

__global__ __launch_bounds__(256) void chan_stats_fb(
    const float* __restrict__ f, float* __restrict__ chan_off) {
  const int ch = blockIdx.x;
  const float4* base = (const float4*)(f + (size_t)ch * HW);
  const int n4 = HW / 4;
  float m = -FLT_MAX;
  for (int i = threadIdx.x; i < n4; i += 256) {
    float4 v = base[i];
    m = fmaxf(m, fmaxf(fmaxf(v.x, v.y), fmaxf(v.z, v.w)));
  }
  __shared__ float sred[4];
  __shared__ float bcast;
  const int wid = threadIdx.x >> 6, lid = threadIdx.x & 63;
  float wm = waveMax(m);
  if (lid == 0) sred[wid] = wm;
  __syncthreads();
  if (threadIdx.x == 0)
    bcast = fmaxf(fmaxf(sred[0], sred[1]), fmaxf(sred[2], sred[3]));
  __syncthreads();
  const float M = bcast;
  float s = 0.f;
  for (int i = threadIdx.x; i < n4; i += 256) {
    float4 v = base[i];
    s += __expf(v.x - M) + __expf(v.y - M) + __expf(v.z - M) + __expf(v.w - M);
  }
  float wsv = waveSum(s);
  __syncthreads();
  if (lid == 0) sred[wid] = wsv;
  __syncthreads();
  if (threadIdx.x == 0)
    chan_off[ch] = M + logf(sred[0] + sred[1] + sred[2] + sred[3]);
}

__global__ __launch_bounds__(256) void pixel_fb(
    const float* __restrict__ f, const int* __restrict__ target,
    const int* __restrict__ parcel, const float* __restrict__ chan_off,
    float* __restrict__ seg_sum, float* __restrict__ counts,
    int* __restrict__ tgtp, float* __restrict__ div_acc) {
  const int t4 = blockIdx.x * 256 + threadIdx.x;
  const int img = t4 / (HW / 4);
  const int pix0 = (t4 % (HW / 4)) * 4;
  const float* fb = f + (size_t)img * C * HW;
  __shared__ float soff[C];
  if (threadIdx.x < C) soff[threadIdx.x] = chan_off[img * C + threadIdx.x];
  __syncthreads();
  const int4 tv = *(const int4*)(target + (size_t)img * HW + pix0);
  const int4 pv = *(const int4*)(parcel + (size_t)img * HW + pix0);
  int tarr[4] = {tv.x, tv.y, tv.z, tv.w};
  int parr[4] = {pv.x, pv.y, pv.z, pv.w};
  bool val[4];
#pragma unroll
  for (int i = 0; i < 4; i++) val[i] = (tarr[i] != IGNORE_INDEX);
  float divs = 0.f;
#pragma unroll
  for (int k = 0; k < NC; k++) {
    float4 dmax = make_float4(-FLT_MAX, -FLT_MAX, -FLT_MAX, -FLT_MAX);
    float4 em = make_float4(-FLT_MAX, -FLT_MAX, -FLT_MAX, -FLT_MAX);
#pragma unroll
    for (int j = 0; j < CNUM; j++) {
      const int ch = k * CNUM + j;
      float4 v = *(const float4*)(fb + (size_t)ch * HW + pix0);
      const float off = soff[ch];
      dmax.x = fmaxf(dmax.x, v.x); dmax.y = fmaxf(dmax.y, v.y);
      dmax.z = fmaxf(dmax.z, v.z); dmax.w = fmaxf(dmax.w, v.w);
      em.x = fmaxf(em.x, v.x - off); em.y = fmaxf(em.y, v.y - off);
      em.z = fmaxf(em.z, v.z - off); em.w = fmaxf(em.w, v.w - off);
    }
    divs += __expf(em.x) + __expf(em.y) + __expf(em.z) + __expf(em.w);
    float dmv[4] = {dmax.x, dmax.y, dmax.z, dmax.w};
#pragma unroll
    for (int i = 0; i < 4; i++)
      if (val[i]) atomicAdd(&seg_sum[parr[i] * NC + k], dmv[i]);
  }
#pragma unroll
  for (int i = 0; i < 4; i++) {
    if (val[i]) {
      atomicAdd(&counts[parr[i]], 1.0f);
      atomicMax(&tgtp[parr[i]], tarr[i]);
    }
  }
  __shared__ float sred[4];
  const int wid = threadIdx.x >> 6, lid = threadIdx.x & 63;
  float wsum = waveSum(divs);
  if (lid == 0) sred[wid] = wsum;
  __syncthreads();
  if (threadIdx.x == 0)
    atomicAdd(div_acc, sred[0] + sred[1] + sred[2] + sred[3]);
}

__global__ __launch_bounds__(256) void seg_fb(
    const float* __restrict__ seg_sum, const float* __restrict__ counts,
    const int* __restrict__ tgtp, float* __restrict__ nll_acc,
    float* __restrict__ vcnt_acc) {
  const int s = blockIdx.x * 256 + threadIdx.x;
  const float cntv = counts[s];
  const float valid = (cntv > 0.f) ? 1.f : 0.f;
  const float inv = 1.f / fmaxf(cntv, 1.f);
  float mean[NC];
  float m = -FLT_MAX;
#pragma unroll
  for (int k = 0; k < NC; k++) {
    mean[k] = seg_sum[s * NC + k] * inv;
    m = fmaxf(m, mean[k]);
  }
  float se = 0.f;
#pragma unroll
  for (int k = 0; k < NC; k++) se += __expf(mean[k] - m);
  const float lse = m + logf(se);
  int t = tgtp[s];
  t = min(max(t, 0), NC - 1);
  const float nll = (lse - mean[t]) * valid;
  __shared__ float sn[4], sv[4];
  const int wid = threadIdx.x >> 6, lid = threadIdx.x & 63;
  float wn = waveSum(nll);
  float wv = waveSum(valid);
  if (lid == 0) { sn[wid] = wn; sv[wid] = wv; }
  __syncthreads();
  if (threadIdx.x == 0) {
    atomicAdd(nll_acc, sn[0] + sn[1] + sn[2] + sn[3]);
    atomicAdd(vcnt_acc, sv[0] + sv[1] + sv[2] + sv[3]);
  }
}

// ================= launch =================
extern "C" void kernel_launch(void* const* d_in, const int* in_sizes, int n_in,
                              void* d_out, int out_size, void* d_ws,
                              size_t ws_size, hipStream_t stream) {
  const float* features = (const float*)d_in[0];
  const int*   target   = (const int*)d_in[1];
  const int*   parcel   = (const int*)d_in[2];
  float* out = (float*)d_out;
  char* wsb = (char*)d_ws;

  if (ws_size >= NEED) {
    float*    bd     = (float*)(wsb + B_BD);
    unsigned* sorted = (unsigned*)(wsb + B_SORT);
    int*      cnt    = (int*)(wsb + B_CNT);
    float*    acc    = (float*)(wsb + B_ACC);  // [div, nll, vcnt]
    int*      offs   = (int*)(wsb + B_OFF);
    int*      woff   = (int*)(wsb + B_WOFF);
    float*    pm     = (float*)(wsb + B_PM);
    float*    ps     = (float*)(wsb + B_PS);
    float*    choff  = (float*)(wsb + B_CHOFF);

    hipMemsetAsync(wsb + B_CNT, 0, P * 4 + 64, stream);  // cnt + acc

    stats_kernel<<<NCH * STRIPES, 256, 0, stream>>>(features, pm, ps);
    combine_kernel<<<1, 640, 0, stream>>>(pm, ps, choff);
    hist_kernel<<<NPIX / 4 / 256, 256, 0, stream>>>(target, parcel, cnt);
    scan_kernel<<<1, 1024, 0, stream>>>(cnt, offs, woff);
    scatter_kernel<<<NPIX / 4 / 256, 256, 0, stream>>>(target, parcel, woff,
                                                       sorted);
    divbd_kernel<<<NPIX / 256, 256, 0, stream>>>(features, choff, bd, acc + 0);
    parcel_kernel<<<P / 4, 256, 0, stream>>>(bd, sorted, cnt, offs, acc);
    finalize_kernel<<<1, 1, 0, stream>>>(acc, out);
  } else {
    float* ws       = (float*)d_ws;
    float* seg_sum  = ws + OFF_SEGSUM;
    float* counts   = ws + OFF_COUNTS;
    float* chan_off = ws + OFF_CHOFF;
    float* acc      = ws + OFF_ACC;
    int*   tgtp     = (int*)(wsb + BYTE_TGT);

    hipMemsetAsync(d_ws, 0, BYTE_ZERO, stream);
    hipMemsetAsync(wsb + BYTE_TGT, 0xFF, BYTE_TGT_N, stream);
    chan_stats_fb<<<NCH, 256, 0, stream>>>(features, chan_off);
    pixel_fb<<<NPIX / 4 / 256, 256, 0, stream>>>(features, target, parcel,
                                                 chan_off, seg_sum, counts,
                                                 tgtp, acc + 0);
    seg_fb<<<P / 256, 256, 0, stream>>>(seg_sum, counts, tgtp, acc + 1,
                                        acc + 2);
    finalize_kernel<<<1, 1, 0, stream>>>(acc, out);
  }
}

// Round 3
// 382.941 us; speedup vs baseline: 2.2094x; 1.0743x over previous
//
#include <hip/hip_runtime.h>
#include <float.h>

#define IGNORE_INDEX 255

constexpr int N_IMG = 8;
constexpr int C     = 80;     // num_class * cnum
constexpr int HW    = 65536;  // 256*256
constexpr int NC    = 20;     // num_class
constexpr int CNUM  = 4;
constexpr int P     = 8192;   // parcel segments
constexpr int NPIX  = N_IMG * HW;  // 524288
constexpr int STRIPES = 4;
constexpr int NCH   = N_IMG * C;   // 640

// ---- sort-path workspace layout (bytes) ----
constexpr size_t B_BDS   = 0;                                 // NPIX*20 floats (sorted rows)
constexpr size_t B_CNT   = (size_t)NPIX * 20 * 4;             // 41943040, 16B aligned
constexpr size_t B_ACC   = B_CNT + (size_t)P * 4;             // memset covers CNT+ACC
constexpr size_t B_OFF   = B_ACC + 64;
constexpr size_t B_WOFF  = B_OFF + (size_t)P * 4;
constexpr size_t B_PM    = B_WOFF + (size_t)P * 4;
constexpr size_t B_PS    = B_PM + (size_t)NCH * STRIPES * 4;
constexpr size_t B_CHOFF = B_PS + (size_t)NCH * STRIPES * 4;
constexpr size_t B_TGT   = B_CHOFF + (size_t)NCH * 4;
constexpr size_t NEED    = B_TGT + (size_t)P * 4;             // ~42.1 MB

__device__ __forceinline__ float waveMax(float v) {
#pragma unroll
  for (int o = 32; o > 0; o >>= 1) v = fmaxf(v, __shfl_down(v, o, 64));
  return v;
}
__device__ __forceinline__ float waveSum(float v) {
#pragma unroll
  for (int o = 32; o > 0; o >>= 1) v += __shfl_down(v, o, 64);
  return v;
}

// K1: blocks [0, 2560): per-(channel,stripe) softmax partial stats.
//     blocks [2560, 3072): parcel histogram (rides along the streaming pass).
__global__ __launch_bounds__(256) void stats_hist_kernel(
    const float* __restrict__ f, const int* __restrict__ target,
    const int* __restrict__ parcel, float* __restrict__ pm,
    float* __restrict__ ps, int* __restrict__ cnt) {
  if (blockIdx.x >= NCH * STRIPES) {
    const int t4 = (blockIdx.x - NCH * STRIPES) * 256 + threadIdx.x;
    const int4 tv = ((const int4*)target)[t4];
    const int4 pv = ((const int4*)parcel)[t4];
    if (tv.x != IGNORE_INDEX) atomicAdd(&cnt[pv.x], 1);
    if (tv.y != IGNORE_INDEX) atomicAdd(&cnt[pv.y], 1);
    if (tv.z != IGNORE_INDEX) atomicAdd(&cnt[pv.z], 1);
    if (tv.w != IGNORE_INDEX) atomicAdd(&cnt[pv.w], 1);
    return;
  }
  const int ch = blockIdx.x >> 2, stripe = blockIdx.x & 3;
  const float4* base =
      (const float4*)(f + (size_t)ch * HW + (size_t)stripe * (HW / STRIPES));
  const int n4 = HW / STRIPES / 4;  // 4096
  float m = -FLT_MAX;
  for (int i = threadIdx.x; i < n4; i += 256) {
    float4 v = base[i];
    m = fmaxf(m, fmaxf(fmaxf(v.x, v.y), fmaxf(v.z, v.w)));
  }
  __shared__ float sred[4];
  __shared__ float bcast;
  const int wid = threadIdx.x >> 6, lid = threadIdx.x & 63;
  float wm = waveMax(m);
  if (lid == 0) sred[wid] = wm;
  __syncthreads();
  if (threadIdx.x == 0)
    bcast = fmaxf(fmaxf(sred[0], sred[1]), fmaxf(sred[2], sred[3]));
  __syncthreads();
  const float M = bcast;
  float s = 0.f;
  for (int i = threadIdx.x; i < n4; i += 256) {
    float4 v = base[i];  // 64KB chunk: L2-hit re-read
    s += __expf(v.x - M) + __expf(v.y - M) + __expf(v.z - M) + __expf(v.w - M);
  }
  float wsv = waveSum(s);
  __syncthreads();
  if (lid == 0) sred[wid] = wsv;
  __syncthreads();
  if (threadIdx.x == 0) {
    pm[blockIdx.x] = M;
    ps[blockIdx.x] = sred[0] + sred[1] + sred[2] + sred[3];
  }
}

// K2: one block of 1024: combine stripe stats (threads < 640) + exclusive
//     scan of cnt[8192] -> offs, woff.
__global__ __launch_bounds__(1024) void combine_scan_kernel(
    const float* __restrict__ pm, const float* __restrict__ ps,
    float* __restrict__ choff, const int* __restrict__ cnt,
    int* __restrict__ offs, int* __restrict__ woff) {
  const int t = threadIdx.x;
  if (t < NCH) {
    float m = -FLT_MAX;
#pragma unroll
    for (int i = 0; i < STRIPES; i++) m = fmaxf(m, pm[t * STRIPES + i]);
    float s = 0.f;
#pragma unroll
    for (int i = 0; i < STRIPES; i++)
      s += ps[t * STRIPES + i] * __expf(pm[t * STRIPES + i] - m);
    choff[t] = m + logf(s);
  }
  __shared__ int sh[1024];
  const int4* c4 = (const int4*)(cnt + t * 8);
  int4 a = c4[0], b = c4[1];
  int c[8] = {a.x, a.y, a.z, a.w, b.x, b.y, b.z, b.w};
  int tot = 0;
#pragma unroll
  for (int j = 0; j < 8; j++) tot += c[j];
  sh[t] = tot;
  __syncthreads();
  for (int d = 1; d < 1024; d <<= 1) {
    int v = (t >= d) ? sh[t - d] : 0;
    __syncthreads();
    sh[t] += v;
    __syncthreads();
  }
  int e = sh[t] - tot;
#pragma unroll
  for (int j = 0; j < 8; j++) {
    offs[t * 8 + j] = e;
    woff[t * 8 + j] = e;
    e += c[j];
  }
}

// K3: per-pixel group-max + diversity term + in-kernel scatter: writes the
//     20-float bd row directly at its sorted position. tgtp via plain store
//     (labels are parcel-constant; any valid writer gives segment_max).
__global__ __launch_bounds__(256) void divbd_scatter_kernel(
    const float* __restrict__ f, const int* __restrict__ target,
    const int* __restrict__ parcel, const float* __restrict__ choff,
    int* __restrict__ woff, float* __restrict__ bds, int* __restrict__ tgtp,
    float* __restrict__ div_acc) {
  const int pg = blockIdx.x * 256 + threadIdx.x;
  const int img = pg >> 16;
  const int pix = pg & (HW - 1);
  const float* fb = f + (size_t)img * C * HW + pix;
  __shared__ float soff[C];
  if (threadIdx.x < C) soff[threadIdx.x] = choff[img * C + threadIdx.x];
  __syncthreads();
  float dm[NC];
  float divs = 0.f;
#pragma unroll
  for (int k = 0; k < NC; k++) {
    float d = -FLT_MAX, e = -FLT_MAX;
#pragma unroll
    for (int j = 0; j < CNUM; j++) {
      const int ch = k * CNUM + j;
      float v = fb[(size_t)ch * HW];
      d = fmaxf(d, v);
      e = fmaxf(e, v - soff[ch]);  // max(exp(x-off)) == exp(max(x-off))
    }
    dm[k] = d;
    divs += __expf(e);
  }
  const int t = target[pg];
  const int p = parcel[pg];
  if (t != IGNORE_INDEX) {
    const int pos = atomicAdd(&woff[p], 1);
    float4* o = (float4*)(bds + (size_t)pos * NC);
    o[0] = make_float4(dm[0], dm[1], dm[2], dm[3]);
    o[1] = make_float4(dm[4], dm[5], dm[6], dm[7]);
    o[2] = make_float4(dm[8], dm[9], dm[10], dm[11]);
    o[3] = make_float4(dm[12], dm[13], dm[14], dm[15]);
    o[4] = make_float4(dm[16], dm[17], dm[18], dm[19]);
    tgtp[p] = t;
  }
  __shared__ float sred[4];
  const int wid = threadIdx.x >> 6, lid = threadIdx.x & 63;
  float wsum = waveSum(divs);
  if (lid == 0) sred[wid] = wsum;
  __syncthreads();
  if (threadIdx.x == 0)
    atomicAdd(div_acc, sred[0] + sred[1] + sred[2] + sred[3]);
}

// K4: one wave per parcel, fully-coalesced streaming of its contiguous rows.
__global__ __launch_bounds__(256) void parcel_kernel(
    const float* __restrict__ bds, const int* __restrict__ cnt,
    const int* __restrict__ offs, const int* __restrict__ tgtp,
    float* __restrict__ acc) {
  const int wid = threadIdx.x >> 6, lid = threadIdx.x & 63;
  const int p = blockIdx.x * 4 + wid;
  const int c = cnt[p];
  float sums[NC];
#pragma unroll
  for (int k = 0; k < NC; k++) sums[k] = 0.f;
  if (c > 0) {
    const int start = offs[p];
    for (int i = lid; i < c; i += 64) {
      const float4* b = (const float4*)(bds + (size_t)(start + i) * NC);
      float4 b0 = b[0], b1 = b[1], b2 = b[2], b3 = b[3], b4 = b[4];
      sums[0] += b0.x;  sums[1] += b0.y;  sums[2] += b0.z;  sums[3] += b0.w;
      sums[4] += b1.x;  sums[5] += b1.y;  sums[6] += b1.z;  sums[7] += b1.w;
      sums[8] += b2.x;  sums[9] += b2.y;  sums[10] += b2.z; sums[11] += b2.w;
      sums[12] += b3.x; sums[13] += b3.y; sums[14] += b3.z; sums[15] += b3.w;
      sums[16] += b4.x; sums[17] += b4.y; sums[18] += b4.z; sums[19] += b4.w;
    }
  }
#pragma unroll
  for (int o = 32; o > 0; o >>= 1) {
#pragma unroll
    for (int k = 0; k < NC; k++) sums[k] += __shfl_xor(sums[k], o, 64);
  }
  float nll = 0.f, val = 0.f;
  if (c > 0) {
    const float inv = 1.f / (float)c;
    float mean[NC];
    float m = -FLT_MAX;
#pragma unroll
    for (int k = 0; k < NC; k++) {
      mean[k] = sums[k] * inv;
      m = fmaxf(m, mean[k]);
    }
    float se = 0.f;
#pragma unroll
    for (int k = 0; k < NC; k++) se += __expf(mean[k] - m);
    const float lse = m + logf(se);
    const int t = min(max(tgtp[p], 0), NC - 1);
    nll = lse - mean[t];
    val = 1.f;
  }
  __shared__ float sn[4], sv[4];
  if (lid == 0) { sn[wid] = nll; sv[wid] = val; }
  __syncthreads();
  if (threadIdx.x == 0) {
    atomicAdd(&acc[1], sn[0] + sn[1] + sn[2] + sn[3]);
    atomicAdd(&acc[2], sv[0] + sv[1] + sv[2] + sv[3]);
  }
}

// K5: scalars out. acc: [0]=div_sum [1]=nll_sum [2]=valid_cnt
__global__ void finalize_kernel(const float* __restrict__ acc,
                                float* __restrict__ out) {
  out[0] = acc[1] / fmaxf(acc[2], 1.f);
  out[1] = 1.f - acc[0] / (float)(N_IMG * NC * NC);
}

// ================= fallback path (R1 code, needs ~723KB ws) =================
constexpr size_t OFF_SEGSUM = 0;
constexpr size_t OFF_COUNTS = 163840;
constexpr size_t OFF_CHOFF  = 172032;
constexpr size_t OFF_ACC    = 172672;
constexpr size_t BYTE_TGT   = 690752;
constexpr size_t BYTE_ZERO  = 690752;
constexpr size_t BYTE_TGT_N = P * sizeof(int);

__global__ __launch_bounds__(256) void chan_stats_fb(
    const float* __restrict__ f, float* __restrict__ chan_off) {
  const int ch = blockIdx.x;
  const float4* base = (const float4*)(f + (size_t)ch * HW);
  const int n4 = HW / 4;
  float m = -FLT_MAX;
  for (int i = threadIdx.x; i < n4; i += 256) {
    float4 v = base[i];
    m = fmaxf(m, fmaxf(fmaxf(v.x, v.y), fmaxf(v.z, v.w)));
  }
  __shared__ float sred[4];
  __shared__ float bcast;
  const int wid = threadIdx.x >> 6, lid = threadIdx.x & 63;
  float wm = waveMax(m);
  if (lid == 0) sred[wid] = wm;
  __syncthreads();
  if (threadIdx.x == 0)
    bcast = fmaxf(fmaxf(sred[0], sred[1]), fmaxf(sred[2], sred[3]));
  __syncthreads();
  const float M = bcast;
  float s = 0.f;
  for (int i = threadIdx.x; i < n4; i += 256) {
    float4 v = base[i];
    s += __expf(v.x - M) + __expf(v.y - M) + __expf(v.z - M) + __expf(v.w - M);
  }
  float wsv = waveSum(s);
  __syncthreads();
  if (lid == 0) sred[wid] = wsv;
  __syncthreads();
  if (threadIdx.x == 0)
    chan_off[ch] = M + logf(sred[0] + sred[1] + sred[2] + sred[3]);
}

__global__ __launch_bounds__(256) void pixel_fb(
    const float* __restrict__ f, const int* __restrict__ target,
    const int* __restrict__ parcel, const float* __restrict__ chan_off,
    float* __restrict__ seg_sum, float* __restrict__ counts,
    int* __restrict__ tgtp, float* __restrict__ div_acc) {
  const int t4 = blockIdx.x * 256 + threadIdx.x;
  const int img = t4 / (HW / 4);
  const int pix0 = (t4 % (HW / 4)) * 4;
  const float* fb = f + (size_t)img * C * HW;
  __shared__ float soff[C];
  if (threadIdx.x < C) soff[threadIdx.x] = chan_off[img * C + threadIdx.x];
  __syncthreads();
  const int4 tv = *(const int4*)(target + (size_t)img * HW + pix0);
  const int4 pv = *(const int4*)(parcel + (size_t)img * HW + pix0);
  int tarr[4] = {tv.x, tv.y, tv.z, tv.w};
  int parr[4] = {pv.x, pv.y, pv.z, pv.w};
  bool val[4];
#pragma unroll
  for (int i = 0; i < 4; i++) val[i] = (tarr[i] != IGNORE_INDEX);
  float divs = 0.f;
#pragma unroll
  for (int k = 0; k < NC; k++) {
    float4 dmax = make_float4(-FLT_MAX, -FLT_MAX, -FLT_MAX, -FLT_MAX);
    float4 em = make_float4(-FLT_MAX, -FLT_MAX, -FLT_MAX, -FLT_MAX);
#pragma unroll
    for (int j = 0; j < CNUM; j++) {
      const int ch = k * CNUM + j;
      float4 v = *(const float4*)(fb + (size_t)ch * HW + pix0);
      const float off = soff[ch];
      dmax.x = fmaxf(dmax.x, v.x); dmax.y = fmaxf(dmax.y, v.y);
      dmax.z = fmaxf(dmax.z, v.z); dmax.w = fmaxf(dmax.w, v.w);
      em.x = fmaxf(em.x, v.x - off); em.y = fmaxf(em.y, v.y - off);
      em.z = fmaxf(em.z, v.z - off); em.w = fmaxf(em.w, v.w - off);
    }
    divs += __expf(em.x) + __expf(em.y) + __expf(em.z) + __expf(em.w);
    float dmv[4] = {dmax.x, dmax.y, dmax.z, dmax.w};
#pragma unroll
    for (int i = 0; i < 4; i++)
      if (val[i]) atomicAdd(&seg_sum[parr[i] * NC + k], dmv[i]);
  }
#pragma unroll
  for (int i = 0; i < 4; i++) {
    if (val[i]) {
      atomicAdd(&counts[parr[i]], 1.0f);
      atomicMax(&tgtp[parr[i]], tarr[i]);
    }
  }
  __shared__ float sred[4];
  const int wid = threadIdx.x >> 6, lid = threadIdx.x & 63;
  float wsum = waveSum(divs);
  if (lid == 0) sred[wid] = wsum;
  __syncthreads();
  if (threadIdx.x == 0)
    atomicAdd(div_acc, sred[0] + sred[1] + sred[2] + sred[3]);
}

__global__ __launch_bounds__(256) void seg_fb(
    const float* __restrict__ seg_sum, const float* __restrict__ counts,
    const int* __restrict__ tgtp, float* __restrict__ nll_acc,
    float* __restrict__ vcnt_acc) {
  const int s = blockIdx.x * 256 + threadIdx.x;
  const float cntv = counts[s];
  const float valid = (cntv > 0.f) ? 1.f : 0.f;
  const float inv = 1.f / fmaxf(cntv, 1.f);
  float mean[NC];
  float m = -FLT_MAX;
#pragma unroll
  for (int k = 0; k < NC; k++) {
    mean[k] = seg_sum[s * NC + k] * inv;
    m = fmaxf(m, mean[k]);
  }
  float se = 0.f;
#pragma unroll
  for (int k = 0; k < NC; k++) se += __expf(mean[k] - m);
  const float lse = m + logf(se);
  int t = tgtp[s];
  t = min(max(t, 0), NC - 1);
  const float nll = (lse - mean[t]) * valid;
  __shared__ float sn[4], sv[4];
  const int wid = threadIdx.x >> 6, lid = threadIdx.x & 63;
  float wn = waveSum(nll);
  float wv = waveSum(valid);
  if (lid == 0) { sn[wid] = wn; sv[wid] = wv; }
  __syncthreads();
  if (threadIdx.x == 0) {
    atomicAdd(nll_acc, sn[0] + sn[1] + sn[2] + sn[3]);
    atomicAdd(vcnt_acc, sv[0] + sv[1] + sv[2] + sv[3]);
  }
}

// ================= launch =================
extern "C" void kernel_launch(void* const* d_in, const int* in_sizes, int n_in,
                              void* d_out, int out_size, void* d_ws,
                              size_t ws_size, hipStream_t stream) {
  const float* features = (const float*)d_in[0];
  const int*   target   = (const int*)d_in[1];
  const int*   parcel   = (const int*)d_in[2];
  float* out = (float*)d_out;
  char* wsb = (char*)d_ws;

  if (ws_size >= NEED) {
    float* bds   = (float*)(wsb + B_BDS);
    int*   cnt   = (int*)(wsb + B_CNT);
    float* acc   = (float*)(wsb + B_ACC);  // [div, nll, vcnt]
    int*   offs  = (int*)(wsb + B_OFF);
    int*   woff  = (int*)(wsb + B_WOFF);
    float* pm    = (float*)(wsb + B_PM);
    float* ps    = (float*)(wsb + B_PS);
    float* choff = (float*)(wsb + B_CHOFF);
    int*   tgtp  = (int*)(wsb + B_TGT);

    hipMemsetAsync(wsb + B_CNT, 0, P * 4 + 64, stream);  // cnt + acc

    stats_hist_kernel<<<NCH * STRIPES + NPIX / 1024, 256, 0, stream>>>(
        features, target, parcel, pm, ps, cnt);
    combine_scan_kernel<<<1, 1024, 0, stream>>>(pm, ps, choff, cnt, offs,
                                                woff);
    divbd_scatter_kernel<<<NPIX / 256, 256, 0, stream>>>(
        features, target, parcel, choff, woff, bds, tgtp, acc + 0);
    parcel_kernel<<<P / 4, 256, 0, stream>>>(bds, cnt, offs, tgtp, acc);
    finalize_kernel<<<1, 1, 0, stream>>>(acc, out);
  } else {
    float* ws       = (float*)d_ws;
    float* seg_sum  = ws + OFF_SEGSUM;
    float* counts   = ws + OFF_COUNTS;
    float* chan_off = ws + OFF_CHOFF;
    float* acc      = ws + OFF_ACC;
    int*   tgtp     = (int*)(wsb + BYTE_TGT);

    hipMemsetAsync(d_ws, 0, BYTE_ZERO, stream);
    hipMemsetAsync(wsb + BYTE_TGT, 0xFF, BYTE_TGT_N, stream);
    chan_stats_fb<<<NCH, 256, 0, stream>>>(features, chan_off);
    pixel_fb<<<NPIX / 4 / 256, 256, 0, stream>>>(features, target, parcel,
                                                 chan_off, seg_sum, counts,
                                                 tgtp, acc + 0);
    seg_fb<<<P / 256, 256, 0, stream>>>(seg_sum, counts, tgtp, acc + 1,
                                        acc + 2);
    finalize_kernel<<<1, 1, 0, stream>>>(acc, out);
  }
}